// Round 6
// baseline (1354.098 us; speedup 1.0000x reference)
//
#include <hip/hip_runtime.h>
#include <hip/hip_bf16.h>
#include <cstdint>

#define B_ 8
#define L_ 2048
#define D_ 1024
#define Z_ 128
#define V_ 2048
#define N_ 16
#define NC_ 16
#define CL_ 128

typedef unsigned short ushort_t;
typedef __attribute__((ext_vector_type(8))) short short8;
typedef __attribute__((ext_vector_type(4))) float floatx4;

__device__ __forceinline__ float b2f(ushort_t u){ union{float f;unsigned i;}x; x.i=((unsigned)u)<<16; return x.f; }
__device__ __forceinline__ ushort_t f2b(float f){ union{float f;unsigned i;}x; x.f=f; unsigned r=(x.i+0x7fffu+((x.i>>16)&1u))>>16; return (ushort_t)r; }
__device__ __forceinline__ float sigmoidf_(float x){ return 1.0f/(1.0f+__expf(-x)); }
__device__ __forceinline__ float siluf_(float x){ return x/(1.0f+__expf(-x)); }

#define GLL16(g,l) __builtin_amdgcn_global_load_lds( \
    (const __attribute__((address_space(1))) void*)(g), \
    (__attribute__((address_space(3))) void*)(l), 16, 0, 0)

__device__ __forceinline__ float blockSum(float v){
  #pragma unroll
  for(int off=32;off;off>>=1) v += __shfl_xor(v,off);
  __shared__ float sm[4];
  __syncthreads();
  if((threadIdx.x&63)==0) sm[threadIdx.x>>6]=v;
  __syncthreads();
  return (sm[0]+sm[1])+(sm[2]+sm[3]);
}
__device__ __forceinline__ float blockMax(float v){
  #pragma unroll
  for(int off=32;off;off>>=1) v = fmaxf(v,__shfl_xor(v,off));
  __shared__ float sm[4];
  __syncthreads();
  if((threadIdx.x&63)==0) sm[threadIdx.x>>6]=v;
  __syncthreads();
  return fmaxf(fmaxf(sm[0],sm[1]),fmaxf(sm[2],sm[3]));
}

// ---------------- LayerNorm (D=1024, 256 thr x 4) -> bf16 ---------------------
__global__ __launch_bounds__(256) void ln_kernel(const float* __restrict__ in,
    const float* __restrict__ w, const float* __restrict__ b,
    ushort_t* __restrict__ o16){
  const int row = blockIdx.x;
  const int t = threadIdx.x;
  const float* p = in + (size_t)row*D_;
  float4 v = *reinterpret_cast<const float4*>(p + t*4);
  float s = (v.x+v.y)+(v.z+v.w);
  s = blockSum(s);
  float mu = s*(1.0f/D_);
  float dx=v.x-mu, dy=v.y-mu, dz=v.z-mu, dw=v.w-mu;
  float ss = dx*dx+dy*dy+dz*dz+dw*dw;
  ss = blockSum(ss);
  float inv = rsqrtf(ss*(1.0f/D_)+1e-5f);
  float4 wv = *reinterpret_cast<const float4*>(w + t*4);
  float4 bv = *reinterpret_cast<const float4*>(b + t*4);
  union{ushort_t u[4]; uint2 q;} o;
  o.u[0]=f2b(dx*inv*wv.x+bv.x); o.u[1]=f2b(dy*inv*wv.y+bv.y);
  o.u[2]=f2b(dz*inv*wv.z+bv.z); o.u[3]=f2b(dw*inv*wv.w+bv.w);
  *reinterpret_cast<uint2*>(o16+(size_t)row*D_+t*4)=o.q;
}

// ---------------- weight transpose + f32->bf16 (in [R,C] -> out [C,R]) --------
__global__ __launch_bounds__(256) void transpose_w(const float* __restrict__ in,
    ushort_t* __restrict__ out, int R, int C){
  __shared__ float tile[32][33];
  int bx=blockIdx.x*32, by=blockIdx.y*32;
  int tx=threadIdx.x&31, ty=threadIdx.x>>5;
  #pragma unroll
  for(int i=0;i<32;i+=8) tile[ty+i][tx] = in[(size_t)(by+ty+i)*C + bx+tx];
  __syncthreads();
  #pragma unroll
  for(int i=0;i<32;i+=8) out[(size_t)(bx+ty+i)*R + by+tx] = f2b(tile[tx][ty+i]);
}

// ---------------- EMA: setup / chunked scan -----------------------------------
__global__ __launch_bounds__(256) void ema_setup(const float* __restrict__ delta,
    const float* __restrict__ alpha, const float* __restrict__ beta,
    const float* __restrict__ gamma, float* __restrict__ qarr,
    float* __restrict__ warr, float* __restrict__ qC){
  int i = blockIdx.x*256+threadIdx.x;
  if(i>=D_*N_) return;
  float p = sigmoidf_(delta[i]);
  float q = 1.0f - p*sigmoidf_(alpha[i]);
  qarr[i]=q; warr[i]=p*beta[i]*gamma[i]*0.25f; // 1/sqrt(N)=0.25
  qC[i]=powf(q,(float)CL_);
}

__global__ __launch_bounds__(256) void ema_pass1(const ushort_t* __restrict__ xn,
    const float* __restrict__ qarr, float* __restrict__ E){
  int idx = blockIdx.x*256+threadIdx.x;     // b*16384 + c*1024 + d
  int d = idx & (D_-1); int c = (idx>>10)&15; int b = idx>>14;
  const ushort_t* xp = xn + ((size_t)b*L_ + c*CL_)*D_ + d;
  float q[N_], s[N_];
  #pragma unroll
  for(int n=0;n<N_;n++){ q[n]=qarr[d*N_+n]; s[n]=0.0f; }
  for(int i=0;i<CL_;i+=8){
    float xv[8];
    #pragma unroll
    for(int j=0;j<8;j++) xv[j]=b2f(xp[(size_t)(i+j)*D_]);
    #pragma unroll
    for(int j=0;j<8;j++){
      #pragma unroll
      for(int n=0;n<N_;n++) s[n]=fmaf(q[n],s[n],xv[j]);
    }
  }
  float* Ep = E + (((size_t)b*NC_+c)*N_)*D_ + d;
  #pragma unroll
  for(int n=0;n<N_;n++) Ep[(size_t)n*D_]=s[n];
}

__global__ __launch_bounds__(256) void ema_pass2(const float* __restrict__ E,
    const float* __restrict__ qC, float* __restrict__ In){
  int idx = blockIdx.x*256+threadIdx.x;     // b*1024 + d
  int d = idx & (D_-1); int b = idx>>10;
  float S[N_], qc[N_];
  #pragma unroll
  for(int n=0;n<N_;n++){ S[n]=0.0f; qc[n]=qC[d*N_+n]; }
  for(int c=0;c<NC_;c++){
    size_t base = (((size_t)b*NC_+c)*N_)*D_ + d;
    #pragma unroll
    for(int n=0;n<N_;n++) In[base+(size_t)n*D_]=S[n];
    #pragma unroll
    for(int n=0;n<N_;n++) S[n]=fmaf(qc[n],S[n],E[base+(size_t)n*D_]);
  }
}

// pass3 fused with mx: mx = silu(ema + xn*omega) -> bf16
__global__ __launch_bounds__(256) void ema_pass3_mx(const ushort_t* __restrict__ xn,
    const float* __restrict__ qarr, const float* __restrict__ warr,
    const float* __restrict__ In, const float* __restrict__ omega,
    ushort_t* __restrict__ mx){
  int idx = blockIdx.x*256+threadIdx.x;
  int d = idx & (D_-1); int c = (idx>>10)&15; int b = idx>>14;
  const ushort_t* xp = xn + ((size_t)b*L_ + c*CL_)*D_ + d;
  ushort_t* op = mx + ((size_t)b*L_ + c*CL_)*D_ + d;
  size_t base = (((size_t)b*NC_+c)*N_)*D_ + d;
  float om = omega[d];
  float q[N_], w[N_], s[N_];
  #pragma unroll
  for(int n=0;n<N_;n++){ q[n]=qarr[d*N_+n]; w[n]=warr[d*N_+n]; s[n]=In[base+(size_t)n*D_]; }
  for(int i=0;i<CL_;i+=8){
    float xv[8];
    #pragma unroll
    for(int j=0;j<8;j++) xv[j]=b2f(xp[(size_t)(i+j)*D_]);
    #pragma unroll
    for(int j=0;j<8;j++){
      float a=0.0f;
      #pragma unroll
      for(int n=0;n<N_;n++){ s[n]=fmaf(q[n],s[n],xv[j]); a=fmaf(w[n],s[n],a); }
      op[(size_t)(i+j)*D_]=f2b(siluf_(a + xv[j]*om));
    }
  }
}

// ---------------- softmax over rows of qk (L cols), write bf16 attn -----------
__global__ __launch_bounds__(256) void softmax_kernel(const float* __restrict__ qk,
    ushort_t* __restrict__ attn){
  size_t row = blockIdx.x;
  const float* p = qk + row*(size_t)L_;
  int t = threadIdx.x;
  float vals[8];
  #pragma unroll
  for(int i=0;i<8;i++) vals[i]=p[i*256+t];
  float m=-__builtin_inff();
  #pragma unroll
  for(int i=0;i<8;i++) m=fmaxf(m,vals[i]);
  m = blockMax(m);
  float s=0.0f;
  #pragma unroll
  for(int i=0;i<8;i++){ vals[i]=__expf(vals[i]-m); s+=vals[i]; }
  s = blockSum(s);
  float inv = 1.0f/s;
  ushort_t* q = attn + row*(size_t)L_;
  #pragma unroll
  for(int i=0;i<8;i++) q[i*256+t]=f2b(vals[i]*inv);
}

// ======================= sync macros (no #pragma inside!) =====================
#define SBAR() do{ __builtin_amdgcn_sched_barrier(0); \
    asm volatile("" ::: "memory"); \
    __builtin_amdgcn_s_barrier(); \
    asm volatile("" ::: "memory"); \
    __builtin_amdgcn_sched_barrier(0); }while(0)
#define VMW(n) asm volatile("s_waitcnt vmcnt(" #n ")" ::: "memory")

// ---------------- OLD engine: NT bf16 GEMM 128x128, BK=64 (kept for QKh/QK) ---
#define BAR_ACQ(vm) do{ \
    asm volatile("s_waitcnt vmcnt(" #vm ")" ::: "memory"); \
    __builtin_amdgcn_s_barrier(); \
    __builtin_amdgcn_sched_barrier(0); }while(0)
#define BAR_REL() do{ \
    __builtin_amdgcn_sched_barrier(0); \
    asm volatile("" ::: "memory"); \
    __builtin_amdgcn_s_barrier(); \
    asm volatile("" ::: "memory"); }while(0)

template<class Epi>
__global__ __launch_bounds__(256) void gemm_nt(const ushort_t* __restrict__ A,
    const ushort_t* __restrict__ B, int M, int N, int K, Epi epi){
  __shared__ __align__(16) ushort_t As[2][128*64];
  __shared__ __align__(16) ushort_t Bs[2][128*64];
  const int t = threadIdx.x;
  const int wave=t>>6, lane=t&63, quad=lane>>4, l16=lane&15;
  const int bm=blockIdx.x*128, bn=blockIdx.y*128;
  const int wm=(wave>>1)*64, wn=(wave&1)*64;
  const int srow = wave*32 + (lane>>3);
  const int schk = ((lane&7) ^ (lane>>3)) * 8;
  const ushort_t* gA[4]; const ushort_t* gB[4];
  ushort_t *lA[4], *lB[4];
  #pragma unroll
  for(int i=0;i<4;i++){
    gA[i] = A + (size_t)(bm+srow+i*8)*K + schk;
    gB[i] = B + (size_t)(bn+srow+i*8)*K + schk;
    lA[i] = &As[0][(wave*32+i*8)*64];
    lB[i] = &Bs[0][(wave*32+i*8)*64];
  }
  const ushort_t* ra[2][4]; const ushort_t* rb[2][4];
  #pragma unroll
  for(int h=0;h<2;h++)
    #pragma unroll
    for(int i=0;i<4;i++){
      int rrA = wm+i*16+l16, rrB = wn+i*16+l16;
      ra[h][i] = &As[0][rrA*64 + (((h*4+quad)^(rrA&7))*8)];
      rb[h][i] = &Bs[0][rrB*64 + (((h*4+quad)^(rrB&7))*8)];
    }
  floatx4 acc[4][4];
  #pragma unroll
  for(int i=0;i<4;i++)
    #pragma unroll
    for(int j=0;j<4;j++) acc[i][j]=(floatx4){0.f,0.f,0.f,0.f};

  const int nk = K>>6;
  #pragma unroll
  for(int i=0;i<4;i++){ GLL16(gA[i], lA[i]); GLL16(gB[i], lB[i]); }

  for(int t0=0;t0<nk;t0+=2){
    {
      const int k0=(t0+1)<<6;
      #pragma unroll
      for(int i=0;i<4;i++){ GLL16(gA[i]+k0, lA[i]+(128*64)); GLL16(gB[i]+k0, lB[i]+(128*64)); }
    }
    BAR_ACQ(8);
    #pragma unroll
    for(int h=0;h<2;h++){
      short8 af[4], bf[4];
      #pragma unroll
      for(int mt=0;mt<4;mt++) af[mt]=*reinterpret_cast<const short8*>(ra[h][mt]);
      #pragma unroll
      for(int nt=0;nt<4;nt++) bf[nt]=*reinterpret_cast<const short8*>(rb[h][nt]);
      #pragma unroll
      for(int mt=0;mt<4;mt++)
        #pragma unroll
        for(int nt=0;nt<4;nt++)
          acc[mt][nt]=__builtin_amdgcn_mfma_f32_16x16x32_bf16(af[mt],bf[nt],acc[mt][nt],0,0,0);
    }
    BAR_REL();
    if(t0+2<nk){
      const int k0=(t0+2)<<6;
      #pragma unroll
      for(int i=0;i<4;i++){ GLL16(gA[i]+k0, lA[i]); GLL16(gB[i]+k0, lB[i]); }
      BAR_ACQ(8);
    } else {
      BAR_ACQ(0);
    }
    #pragma unroll
    for(int h=0;h<2;h++){
      short8 af[4], bf[4];
      #pragma unroll
      for(int mt=0;mt<4;mt++) af[mt]=*reinterpret_cast<const short8*>(ra[h][mt]+(128*64));
      #pragma unroll
      for(int nt=0;nt<4;nt++) bf[nt]=*reinterpret_cast<const short8*>(rb[h][nt]+(128*64));
      #pragma unroll
      for(int mt=0;mt<4;mt++)
        #pragma unroll
        for(int nt=0;nt<4;nt++)
          acc[mt][nt]=__builtin_amdgcn_mfma_f32_16x16x32_bf16(af[mt],bf[nt],acc[mt][nt],0,0,0);
    }
    BAR_REL();
  }

  #pragma unroll
  for(int mt=0;mt<4;mt++)
    #pragma unroll
    for(int nt=0;nt<4;nt++)
      #pragma unroll
      for(int r=0;r<4;r++){
        int row=bm+wm+mt*16+quad*4+r;
        int col=bn+wn+nt*16+l16;
        epi(acc[mt][nt][r], row, col, 0);
      }
}

// ============ NEW engine v3: 256x256, 8 waves, 128-B LDS rows (0-conflict) ====
// C[z][m,n]=sum_k A[z][m,k]*B[z][n,k]. LDS [buf][256 rows][64 elems] per matrix
// (128-B rows), granule g (16B) of row r stored at slot g^(r&7) -> ds_read_b128
// frag reads are conflict-free (quarter-wave: 8 bank-starts x 2 lanes; verified
// zero-conflict in the R0-family layout). gll dest stays linear (lane*16).
// Tile t (4 phases, kh x mh quadrants): P1 {RDA kh0/mh0 + RDB kh0 + STAGE ALL 8
// loads of t+1 -> buf^1; bar; MFMA; bar}, P2 {RDA kh0/mh1; bar; MFMA; bar},
// P3 {RDA kh1/mh0 + RDB kh1; bar; MFMA; bar}, P4 {RDA kh1/mh1; bar; MFMA;
// vmcnt(0); bar}. Cover for the drain = 3 phases (~2-3K cyc) >> HBM latency,
// so vmcnt(0) at tile end is nearly free. Write-after-read safe: stages into
// buf^1 issue after the tile-(t-1)-end barrier that ended all buf^1 reads.
// Raster: supertile 32-block groups (GW x 8) per XCD for A/B L2 reuse (T1).
// Requires M%256==0, N%256==0, K%128==0 (nkt even >=2).

#define RDA(buf,kh,mh) \
  af[0]=pA##kh[(buf)*2048+((mh)*4+0)*128]; \
  af[1]=pA##kh[(buf)*2048+((mh)*4+1)*128]; \
  af[2]=pA##kh[(buf)*2048+((mh)*4+2)*128]; \
  af[3]=pA##kh[(buf)*2048+((mh)*4+3)*128];
#define RDB(buf,kh) \
  bf[0]=pB##kh[(buf)*2048+0*128]; \
  bf[1]=pB##kh[(buf)*2048+1*128]; \
  bf[2]=pB##kh[(buf)*2048+2*128]; \
  bf[3]=pB##kh[(buf)*2048+3*128];
#define MMA16(mh) \
  __builtin_amdgcn_s_setprio(1); \
  acc[(mh)*4+0][0]=__builtin_amdgcn_mfma_f32_16x16x32_bf16(af[0],bf[0],acc[(mh)*4+0][0],0,0,0); \
  acc[(mh)*4+0][1]=__builtin_amdgcn_mfma_f32_16x16x32_bf16(af[0],bf[1],acc[(mh)*4+0][1],0,0,0); \
  acc[(mh)*4+0][2]=__builtin_amdgcn_mfma_f32_16x16x32_bf16(af[0],bf[2],acc[(mh)*4+0][2],0,0,0); \
  acc[(mh)*4+0][3]=__builtin_amdgcn_mfma_f32_16x16x32_bf16(af[0],bf[3],acc[(mh)*4+0][3],0,0,0); \
  acc[(mh)*4+1][0]=__builtin_amdgcn_mfma_f32_16x16x32_bf16(af[1],bf[0],acc[(mh)*4+1][0],0,0,0); \
  acc[(mh)*4+1][1]=__builtin_amdgcn_mfma_f32_16x16x32_bf16(af[1],bf[1],acc[(mh)*4+1][1],0,0,0); \
  acc[(mh)*4+1][2]=__builtin_amdgcn_mfma_f32_16x16x32_bf16(af[1],bf[2],acc[(mh)*4+1][2],0,0,0); \
  acc[(mh)*4+1][3]=__builtin_amdgcn_mfma_f32_16x16x32_bf16(af[1],bf[3],acc[(mh)*4+1][3],0,0,0); \
  acc[(mh)*4+2][0]=__builtin_amdgcn_mfma_f32_16x16x32_bf16(af[2],bf[0],acc[(mh)*4+2][0],0,0,0); \
  acc[(mh)*4+2][1]=__builtin_amdgcn_mfma_f32_16x16x32_bf16(af[2],bf[1],acc[(mh)*4+2][1],0,0,0); \
  acc[(mh)*4+2][2]=__builtin_amdgcn_mfma_f32_16x16x32_bf16(af[2],bf[2],acc[(mh)*4+2][2],0,0,0); \
  acc[(mh)*4+2][3]=__builtin_amdgcn_mfma_f32_16x16x32_bf16(af[2],bf[3],acc[(mh)*4+2][3],0,0,0); \
  acc[(mh)*4+3][0]=__builtin_amdgcn_mfma_f32_16x16x32_bf16(af[3],bf[0],acc[(mh)*4+3][0],0,0,0); \
  acc[(mh)*4+3][1]=__builtin_amdgcn_mfma_f32_16x16x32_bf16(af[3],bf[1],acc[(mh)*4+3][1],0,0,0); \
  acc[(mh)*4+3][2]=__builtin_amdgcn_mfma_f32_16x16x32_bf16(af[3],bf[2],acc[(mh)*4+3][2],0,0,0); \
  acc[(mh)*4+3][3]=__builtin_amdgcn_mfma_f32_16x16x32_bf16(af[3],bf[3],acc[(mh)*4+3][3],0,0,0); \
  __builtin_amdgcn_s_setprio(0);
#define STG8(buf,k0) \
  GLL16(gA[0]+(k0), lA[0]+(buf)*16384); GLL16(gA[1]+(k0), lA[1]+(buf)*16384); \
  GLL16(gA[2]+(k0), lA[2]+(buf)*16384); GLL16(gA[3]+(k0), lA[3]+(buf)*16384); \
  GLL16(gB[0]+(k0), lB[0]+(buf)*16384); GLL16(gB[1]+(k0), lB[1]+(buf)*16384); \
  GLL16(gB[2]+(k0), lB[2]+(buf)*16384); GLL16(gB[3]+(k0), lB[3]+(buf)*16384);

#define TILE_S(buf,k0n) { \
  short8 af[4], bf[4]; \
  RDA(buf,0,0) RDB(buf,0) \
  STG8((buf)^1, k0n) \
  SBAR(); MMA16(0) SBAR(); \
  RDA(buf,0,1) \
  SBAR(); MMA16(1) SBAR(); \
  RDA(buf,1,0) RDB(buf,1) \
  SBAR(); MMA16(0) SBAR(); \
  RDA(buf,1,1) \
  SBAR(); MMA16(1) VMW(0); SBAR(); \
}
#define TILE_L(buf) { \
  short8 af[4], bf[4]; \
  RDA(buf,0,0) RDB(buf,0) \
  SBAR(); MMA16(0) SBAR(); \
  RDA(buf,0,1) \
  SBAR(); MMA16(1) SBAR(); \
  RDA(buf,1,0) RDB(buf,1) \
  SBAR(); MMA16(0) SBAR(); \
  RDA(buf,1,1) \
  SBAR(); MMA16(1) \
}

template<class Epi>
__global__ __launch_bounds__(512) void gemm_nt2(const ushort_t* __restrict__ A0,
    const ushort_t* __restrict__ B0, int M, int N, int K,
    size_t za, size_t zb, Epi epi){
  __shared__ __align__(16) ushort_t As[2*256*64];   // [buf][256 rows][64]
  __shared__ __align__(16) ushort_t Bs[2*256*64];
  const int t = threadIdx.x;
  const int wave=t>>6, lane=t&63, quad=lane>>4, l16=lane&15;
  // ---- rasterization: supertile (GW x 8) = 32 blocks, XCD-chunked ----
  int bx, by;
  {
    int gx=gridDim.x, gy=gridDim.y;
    int f = blockIdx.y*gx + blockIdx.x;
    if((gy==4 || gy==8) && (gx%(32/gy))==0){
      int GW = 32/gy, nst = gx/GW;
      int s, r;
      if((nst&7)==0){ int xc=f&7; int j=f>>3; s = xc*(nst>>3) + (j>>5); r = j&31; }
      else { s = f>>5; r = f&31; }
      bx = s*GW + (r%GW); by = r/GW;
    } else { bx = blockIdx.x; by = blockIdx.y; }
  }
  const int z = blockIdx.z;
  const ushort_t* A = A0 + (size_t)z*za;
  const ushort_t* B = B0 + (size_t)z*zb;
  const int bm=bx*256, bn=by*256;
  const int wm=(wave>>2)*128, wn=(wave&3)*64;
  // staging: gll i covers 8 rows (wave*32+i*8 .. +8); lane l -> row +(l>>3),
  // slot l&7; source granule (l&7)^(l>>3) (pre-swizzled global side).
  const int roff = lane>>3;
  const int goff = ((lane&7)^(lane>>3))*8;
  const ushort_t* gA[4]; const ushort_t* gB[4];
  ushort_t* lA[4]; ushort_t* lB[4];
  #pragma unroll
  for(int i=0;i<4;i++){
    gA[i] = A + (size_t)(bm + wave*32 + i*8 + roff)*K + goff;
    gB[i] = B + (size_t)(bn + wave*32 + i*8 + roff)*K + goff;
    lA[i] = As + (wave*32 + i*8)*64;
    lB[i] = Bs + (wave*32 + i*8)*64;
  }
  // frag read bases (short8 units): row*8 + slot, slot = granule ^ (row&7),
  // granule = kh*4+quad, row&7 == l16&7.
  const short8* pA0 = reinterpret_cast<const short8*>(As) + (wm+l16)*8 + ((quad  )^(l16&7));
  const short8* pA1 = reinterpret_cast<const short8*>(As) + (wm+l16)*8 + ((quad^4)^(l16&7));
  const short8* pB0 = reinterpret_cast<const short8*>(Bs) + (wn+l16)*8 + ((quad  )^(l16&7));
  const short8* pB1 = reinterpret_cast<const short8*>(Bs) + (wn+l16)*8 + ((quad^4)^(l16&7));
  floatx4 acc[8][4];
  #pragma unroll
  for(int i=0;i<8;i++)
    #pragma unroll
    for(int j=0;j<4;j++) acc[i][j]=(floatx4){0.f,0.f,0.f,0.f};

  const int nkt = K>>6;   // even, >=2 for all routed shapes
  // prologue: stage tile 0 into buf0, drain, barrier
  STG8(0, 0)
  VMW(0); SBAR();

  for(int t0=0; t0+2<nkt; t0+=2){
    TILE_S(0,(t0+1)<<6)
    TILE_S(1,(t0+2)<<6)
  }
  TILE_S(0,(nkt-1)<<6)    // computes tile nkt-2, stages last tile
  TILE_L(1)               // last tile: no staging

  #pragma unroll
  for(int mt=0;mt<8;mt++)
    #pragma unroll
    for(int nt=0;nt<4;nt++)
      #pragma unroll
      for(int r=0;r<4;r++){
        int row=bm+wm+mt*16+quad*4+r;
        int col=bn+wn+nt*16+l16;
        epi(acc[mt][nt][r], row, col, z);
      }
}

// ---------------- epilogues (branch-free; pointers pre-offset) ----------------
struct EpiV {            // v = silu(.+vb); store transposed vT[b][col][l]
  ushort_t* vT; const float* vb;
  __device__ void operator()(float v,int row,int col,int) const {
    float s = siluf_(v + vb[col]);
    int b = row>>11, l = row&(L_-1);
    vT[((size_t)b*V_ + col)*L_ + l] = f2b(s);
  }
};
struct EpiU {            // u = sigmoid(.+b) -> bf16
  ushort_t* u; const float* mxb;
  __device__ void operator()(float v,int row,int col,int) const {
    u[(size_t)row*D_+col]=f2b(sigmoidf_(v+mxb[col]));
  }
};
struct EpiQKh {          // z=silu(.+b); qh=z*ag0+ab0, kh=z*ag1+ab1 (col in [0,Z))
  ushort_t* qh; ushort_t* kh; const float* mxb; const float* ag; const float* ab;
  __device__ void operator()(float v,int row,int col,int) const {
    float z=siluf_(v+mxb[col]);
    qh[(size_t)row*Z_+col]=f2b(z*ag[col]+ab[col]);
    kh[(size_t)row*Z_+col]=f2b(z*ag[Z_+col]+ab[Z_+col]);
  }
};
struct EpiR {            // r = silu(.+b) -> bf16
  ushort_t* r; const float* mxb;
  __device__ void operator()(float v,int row,int col,int) const {
    r[(size_t)row*V_+col]=f2b(siluf_(v+mxb[col]));
  }
};
struct EpiHx {           // hx = .+b -> bf16
  ushort_t* hx; const float* mxb;
  __device__ void operator()(float v,int row,int col,int) const {
    hx[(size_t)row*D_+col]=f2b(v+mxb[col]);
  }
};
struct EpiQK {           // qk = scale*dot + rel_bias[L-1+col-row]
  float* qk; const float* rb;
  __device__ void operator()(float v,int row,int col,int) const {
    qk[(size_t)row*L_+col] = v*0.08838834764831845f + rb[L_-1+col-row];
  }
};
struct EpiH {            // hr = (attn@v) * r, in place over r; z = batch in chunk
  ushort_t* hr; const ushort_t* r;
  __device__ void operator()(float v,int row,int col,int z) const {
    size_t idx = ((size_t)z*L_ + row)*V_ + col;
    hr[idx] = f2b(v * b2f(r[idx]));
  }
};
struct EpiOut {          // h2=silu(hx+g+hb); out = x + u*(h2-x)  (out in d_out)
  float* out; const float* x; const ushort_t* u; const ushort_t* hx; const float* hb;
  __device__ void operator()(float v,int row,int col,int) const {
    size_t idx=(size_t)row*D_+col;
    float h2 = siluf_(b2f(hx[idx]) + v + hb[col]);
    float xv = x[idx];
    out[idx] = xv + b2f(u[idx])*(h2-xv);
  }
};
struct EpiF1 {           // f1 = silu(. + ff_b1) -> bf16
  ushort_t* f1; const float* b1;
  __device__ void operator()(float v,int row,int col,int) const {
    f1[(size_t)row*(2*D_)+col]=f2b(siluf_(v+b1[col]));
  }
};
struct EpiFinal {        // d_out += . + ff_b2 (in place)
  float* dout; const float* b2;
  __device__ void operator()(float v,int row,int col,int) const {
    size_t idx=(size_t)row*D_+col;
    dout[idx] = dout[idx] + v + b2[col];
  }
};

// ---------------- host launch -------------------------------------------------
extern "C" void kernel_launch(void* const* d_in, const int* in_sizes, int n_in,
                              void* d_out, int out_size, void* d_ws, size_t ws_size,
                              hipStream_t stream){
  const float* x        = (const float*)d_in[0];
  const float* norm1_w  = (const float*)d_in[1];
  const float* norm1_b  = (const float*)d_in[2];
  const float* ema_delta= (const float*)d_in[3];
  const float* ema_alpha= (const float*)d_in[4];
  const float* ema_beta = (const float*)d_in[5];
  const float* ema_gamma= (const float*)d_in[6];
  const float* ema_omega= (const float*)d_in[7];
  const float* vproj_w  = (const float*)d_in[8];
  const float* vproj_b  = (const float*)d_in[9];
  const float* mx_w     = (const float*)d_in[10];
  const float* mx_b     = (const float*)d_in[11];
  const float* h_w      = (const float*)d_in[12];
  const float* h_b      = (const float*)d_in[13];
  const float* att_gamma= (const float*)d_in[14];
  const float* att_beta = (const float*)d_in[15];
  const float* rel_bias = (const float*)d_in[16];
  const float* norm2_w  = (const float*)d_in[17];
  const float* norm2_b  = (const float*)d_in[18];
  const float* ff_w1    = (const float*)d_in[19];
  const float* ff_b1    = (const float*)d_in[20];
  const float* ff_w2    = (const float*)d_in[21];
  const float* ff_b2    = (const float*)d_in[22];
  float* dout = (float*)d_out;
  char* ws = (char*)d_ws;

  // ---- adaptive workspace layout ----
  size_t cur = 0;
  auto take = [&](size_t b)->size_t{ size_t o=cur; cur += (b+255)&~255ull; return o; };
  const size_t o_wvT  = take((size_t)V_*D_*2);
  const size_t o_wmxT = take((size_t)4224*D_*2);
  const size_t o_whT  = take((size_t)D_*V_*2);
  const size_t o_wf1T = take((size_t)2*D_*D_*2);
  const size_t o_wf2T = take((size_t)D_*2*D_*2);
  const size_t o_qarr = take((size_t)D_*N_*4);
  const size_t o_warr = take((size_t)D_*N_*4);
  const size_t o_qC   = take((size_t)D_*N_*4);
  const size_t globals_end = cur;

  int g = 0;
  size_t o_xn=0,o_mx=0,o_u=0,o_hx=0,o_r=0,o_qh=0,o_kh=0,o_qk=0,o_at=0;
  for(int cand=8; cand>=1; cand>>=1){
    cur = globals_end;
    size_t xn_o = take((size_t)cand*L_*D_*2);
    size_t mx_o = take((size_t)cand*L_*D_*2);
    size_t u_o  = take((size_t)cand*L_*D_*2);
    size_t hx_o = take((size_t)cand*L_*D_*2);
    size_t r_o  = take((size_t)cand*L_*V_*2);
    size_t qh_o = take((size_t)cand*L_*Z_*2);
    size_t kh_o = take((size_t)cand*L_*Z_*2);
    size_t qk_o, at_o;
    if(cand>=4){ qk_o = xn_o; at_o = xn_o + (size_t)L_*L_*4; }   // overlay dead xn/mx
    else { qk_o = take((size_t)L_*L_*4); at_o = take((size_t)L_*L_*2); }
    if(cur <= ws_size){
      g=cand; o_xn=xn_o; o_mx=mx_o; o_u=u_o; o_hx=hx_o; o_r=r_o;
      o_qh=qh_o; o_kh=kh_o; o_qk=qk_o; o_at=at_o; break;
    }
  }
  if(!g) return;   // ws too small even for per-batch plan

  ushort_t* wvT  = (ushort_t*)(ws+o_wvT);
  ushort_t* wmxT = (ushort_t*)(ws+o_wmxT);
  ushort_t* whT  = (ushort_t*)(ws+o_whT);
  ushort_t* wf1T = (ushort_t*)(ws+o_wf1T);
  ushort_t* wf2T = (ushort_t*)(ws+o_wf2T);
  float* qarr = (float*)(ws+o_qarr);
  float* warr = (float*)(ws+o_warr);
  float* qC   = (float*)(ws+o_qC);
  ushort_t* xn  = (ushort_t*)(ws+o_xn);
  ushort_t* mx  = (ushort_t*)(ws+o_mx);
  ushort_t* u16 = (ushort_t*)(ws+o_u);
  ushort_t* hx16= (ushort_t*)(ws+o_hx);
  ushort_t* r16 = (ushort_t*)(ws+o_r);
  ushort_t* qh  = (ushort_t*)(ws+o_qh);
  ushort_t* kh  = (ushort_t*)(ws+o_kh);
  float*    qk  = (float*)   (ws+o_qk);
  ushort_t* attn= (ushort_t*)(ws+o_at);
  float*    E   = (float*)(ws+o_u);    // overlay: E/In used only before u/hx written
  float*    In  = (float*)(ws+o_hx);
  ushort_t* ybf = xn;                  // overlay: xn/qk dead by LN2
  ushort_t* f1  = r16;                 // overlay: r dead after out GEMM

  // attention batching: attn for nbat batches lives in dead mx region (g>=4)
  int nbat; ushort_t* attnB;
  if(g>=4){ nbat = g/2; attnB = mx; }          // g=8 -> 4 batches (32MB <= mx 32MB)
  else    { nbat = 1;   attnB = attn; }

  // ---- one-time prep ----
  transpose_w<<<dim3(V_/32, D_/32), 256, 0, stream>>>(vproj_w, wvT, D_, V_);
  transpose_w<<<dim3(4224/32, D_/32), 256, 0, stream>>>(mx_w, wmxT, D_, 4224);
  transpose_w<<<dim3(D_/32, V_/32), 256, 0, stream>>>(h_w, whT, V_, D_);
  transpose_w<<<dim3((2*D_)/32, D_/32), 256, 0, stream>>>(ff_w1, wf1T, D_, 2*D_);
  transpose_w<<<dim3(D_/32, (2*D_)/32), 256, 0, stream>>>(ff_w2, wf2T, 2*D_, D_);
  ema_setup<<<(D_*N_)/256, 256, 0, stream>>>(ema_delta, ema_alpha, ema_beta, ema_gamma, qarr, warr, qC);

  // ---- per-group pipeline ----
  for(int gi=0; gi<B_/g; ++gi){
    const int RG = g*L_;
    const float* x_g  = x    + (size_t)gi*RG*D_;
    float*       do_g = dout + (size_t)gi*RG*D_;
    ushort_t*    vT   = (ushort_t*)do_g;   // scratch inside d_out slice (dead before out-write)

    ln_kernel<<<RG, 256, 0, stream>>>(x_g, norm1_w, norm1_b, xn);
    ema_pass1<<<(g*NC_*D_)/256, 256, 0, stream>>>(xn, qarr, E);
    ema_pass2<<<(g*D_)/256, 256, 0, stream>>>(E, qC, In);
    ema_pass3_mx<<<(g*NC_*D_)/256, 256, 0, stream>>>(xn, qarr, warr, In, ema_omega, mx);

    { EpiV e{vT, vproj_b};
      gemm_nt2<<<dim3(RG/256, V_/256), 512, 0, stream>>>(xn, wvT, RG, V_, D_, 0, 0, e); }

    // base GEMM split into 4 column sections (branch-free epilogues)
    { EpiU e{u16, mx_b};
      gemm_nt2<<<dim3(RG/256, D_/256), 512, 0, stream>>>(mx, wmxT, RG, D_, D_, 0, 0, e); }
    { EpiQKh e{qh, kh, mx_b+D_, att_gamma, att_beta};
      gemm_nt<<<dim3(RG/128, Z_/128), 256, 0, stream>>>(mx, wmxT+(size_t)D_*D_, RG, Z_, D_, e); }
    { EpiR e{r16, mx_b+D_+Z_};
      gemm_nt2<<<dim3(RG/256, V_/256), 512, 0, stream>>>(mx, wmxT+(size_t)(D_+Z_)*D_, RG, V_, D_, 0, 0, e); }
    { EpiHx e{hx16, mx_b+D_+Z_+V_};
      gemm_nt2<<<dim3(RG/256, D_/256), 512, 0, stream>>>(mx, wmxT+(size_t)(D_+Z_+V_)*D_, RG, D_, D_, 0, 0, e); }

    // attention: per-batch QK+softmax into chunk buffer, then batched PV GEMM
    for(int q0=0; q0<g; q0+=nbat){
      for(int bi=q0; bi<q0+nbat; ++bi){
        { EpiQK e{qk, rel_bias};
          gemm_nt<<<dim3(L_/128, L_/128), 256, 0, stream>>>(
            qh+(size_t)bi*L_*Z_, kh+(size_t)bi*L_*Z_, L_, L_, Z_, e); }
        softmax_kernel<<<L_, 256, 0, stream>>>(qk, attnB+(size_t)(bi-q0)*L_*L_);
      }
      { EpiH e{r16+(size_t)q0*L_*V_, r16+(size_t)q0*L_*V_};
        gemm_nt2<<<dim3(L_/256, V_/256, nbat), 512, 0, stream>>>(
          attnB, vT+(size_t)q0*V_*L_, L_, V_, L_,
          (size_t)L_*L_, (size_t)V_*L_, e); }
    }

    { EpiOut e{do_g, x_g, u16, hx16, h_b};
      gemm_nt2<<<dim3(RG/256, D_/256), 512, 0, stream>>>(r16, whT, RG, D_, V_, 0, 0, e); }
    ln_kernel<<<RG, 256, 0, stream>>>(do_g, norm2_w, norm2_b, ybf);
    { EpiF1 e{f1, ff_b1};
      gemm_nt2<<<dim3(RG/256, (2*D_)/256), 512, 0, stream>>>(ybf, wf1T, RG, 2*D_, D_, 0, 0, e); }
    { EpiFinal e{do_g, ff_b2};
      gemm_nt2<<<dim3(RG/256, D_/256), 512, 0, stream>>>(f1, wf2T, RG, D_, 2*D_, 0, 0, e); }
  }
}

// Round 7
// 1266.634 us; speedup vs baseline: 1.0691x; 1.0691x over previous
//
#include <hip/hip_runtime.h>
#include <hip/hip_bf16.h>
#include <cstdint>

#define B_ 8
#define L_ 2048
#define D_ 1024
#define Z_ 128
#define V_ 2048
#define N_ 16
#define NC_ 16
#define CL_ 128

typedef unsigned short ushort_t;
typedef __attribute__((ext_vector_type(8))) short short8;
typedef __attribute__((ext_vector_type(4))) float floatx4;

__device__ __forceinline__ float b2f(ushort_t u){ union{float f;unsigned i;}x; x.i=((unsigned)u)<<16; return x.f; }
__device__ __forceinline__ ushort_t f2b(float f){ union{float f;unsigned i;}x; x.f=f; unsigned r=(x.i+0x7fffu+((x.i>>16)&1u))>>16; return (ushort_t)r; }
__device__ __forceinline__ float sigmoidf_(float x){ return 1.0f/(1.0f+__expf(-x)); }
__device__ __forceinline__ float siluf_(float x){ return x/(1.0f+__expf(-x)); }

#define GLL16(g,l) __builtin_amdgcn_global_load_lds( \
    (const __attribute__((address_space(1))) void*)(g), \
    (__attribute__((address_space(3))) void*)(l), 16, 0, 0)

__device__ __forceinline__ float blockSum(float v){
  #pragma unroll
  for(int off=32;off;off>>=1) v += __shfl_xor(v,off);
  __shared__ float sm[4];
  __syncthreads();
  if((threadIdx.x&63)==0) sm[threadIdx.x>>6]=v;
  __syncthreads();
  return (sm[0]+sm[1])+(sm[2]+sm[3]);
}
__device__ __forceinline__ float blockMax(float v){
  #pragma unroll
  for(int off=32;off;off>>=1) v = fmaxf(v,__shfl_xor(v,off));
  __shared__ float sm[4];
  __syncthreads();
  if((threadIdx.x&63)==0) sm[threadIdx.x>>6]=v;
  __syncthreads();
  return fmaxf(fmaxf(sm[0],sm[1]),fmaxf(sm[2],sm[3]));
}

// ---------------- LayerNorm (D=1024, 256 thr x 4) -> bf16 ---------------------
__global__ __launch_bounds__(256) void ln_kernel(const float* __restrict__ in,
    const float* __restrict__ w, const float* __restrict__ b,
    ushort_t* __restrict__ o16){
  const int row = blockIdx.x;
  const int t = threadIdx.x;
  const float* p = in + (size_t)row*D_;
  float4 v = *reinterpret_cast<const float4*>(p + t*4);
  float s = (v.x+v.y)+(v.z+v.w);
  s = blockSum(s);
  float mu = s*(1.0f/D_);
  float dx=v.x-mu, dy=v.y-mu, dz=v.z-mu, dw=v.w-mu;
  float ss = dx*dx+dy*dy+dz*dz+dw*dw;
  ss = blockSum(ss);
  float inv = rsqrtf(ss*(1.0f/D_)+1e-5f);
  float4 wv = *reinterpret_cast<const float4*>(w + t*4);
  float4 bv = *reinterpret_cast<const float4*>(b + t*4);
  union{ushort_t u[4]; uint2 q;} o;
  o.u[0]=f2b(dx*inv*wv.x+bv.x); o.u[1]=f2b(dy*inv*wv.y+bv.y);
  o.u[2]=f2b(dz*inv*wv.z+bv.z); o.u[3]=f2b(dw*inv*wv.w+bv.w);
  *reinterpret_cast<uint2*>(o16+(size_t)row*D_+t*4)=o.q;
}

// ---------------- weight transpose + f32->bf16 (in [R,C] -> out [C,R]) --------
__global__ __launch_bounds__(256) void transpose_w(const float* __restrict__ in,
    ushort_t* __restrict__ out, int R, int C){
  __shared__ float tile[32][33];
  int bx=blockIdx.x*32, by=blockIdx.y*32;
  int tx=threadIdx.x&31, ty=threadIdx.x>>5;
  #pragma unroll
  for(int i=0;i<32;i+=8) tile[ty+i][tx] = in[(size_t)(by+ty+i)*C + bx+tx];
  __syncthreads();
  #pragma unroll
  for(int i=0;i<32;i+=8) out[(size_t)(bx+ty+i)*R + by+tx] = f2b(tile[tx][ty+i]);
}

// ---------------- EMA: setup / chunked scan -----------------------------------
__global__ __launch_bounds__(256) void ema_setup(const float* __restrict__ delta,
    const float* __restrict__ alpha, const float* __restrict__ beta,
    const float* __restrict__ gamma, float* __restrict__ qarr,
    float* __restrict__ warr, float* __restrict__ qC){
  int i = blockIdx.x*256+threadIdx.x;
  if(i>=D_*N_) return;
  float p = sigmoidf_(delta[i]);
  float q = 1.0f - p*sigmoidf_(alpha[i]);
  qarr[i]=q; warr[i]=p*beta[i]*gamma[i]*0.25f; // 1/sqrt(N)=0.25
  qC[i]=powf(q,(float)CL_);
}

__global__ __launch_bounds__(256) void ema_pass1(const ushort_t* __restrict__ xn,
    const float* __restrict__ qarr, float* __restrict__ E){
  int idx = blockIdx.x*256+threadIdx.x;     // b*16384 + c*1024 + d
  int d = idx & (D_-1); int c = (idx>>10)&15; int b = idx>>14;
  const ushort_t* xp = xn + ((size_t)b*L_ + c*CL_)*D_ + d;
  float q[N_], s[N_];
  #pragma unroll
  for(int n=0;n<N_;n++){ q[n]=qarr[d*N_+n]; s[n]=0.0f; }
  for(int i=0;i<CL_;i+=8){
    float xv[8];
    #pragma unroll
    for(int j=0;j<8;j++) xv[j]=b2f(xp[(size_t)(i+j)*D_]);
    #pragma unroll
    for(int j=0;j<8;j++){
      #pragma unroll
      for(int n=0;n<N_;n++) s[n]=fmaf(q[n],s[n],xv[j]);
    }
  }
  float* Ep = E + (((size_t)b*NC_+c)*N_)*D_ + d;
  #pragma unroll
  for(int n=0;n<N_;n++) Ep[(size_t)n*D_]=s[n];
}

__global__ __launch_bounds__(256) void ema_pass2(const float* __restrict__ E,
    const float* __restrict__ qC, float* __restrict__ In){
  int idx = blockIdx.x*256+threadIdx.x;     // b*1024 + d
  int d = idx & (D_-1); int b = idx>>10;
  float S[N_], qc[N_];
  #pragma unroll
  for(int n=0;n<N_;n++){ S[n]=0.0f; qc[n]=qC[d*N_+n]; }
  for(int c=0;c<NC_;c++){
    size_t base = (((size_t)b*NC_+c)*N_)*D_ + d;
    #pragma unroll
    for(int n=0;n<N_;n++) In[base+(size_t)n*D_]=S[n];
    #pragma unroll
    for(int n=0;n<N_;n++) S[n]=fmaf(qc[n],S[n],E[base+(size_t)n*D_]);
  }
}

// pass3 fused with mx: mx = silu(ema + xn*omega) -> bf16
__global__ __launch_bounds__(256) void ema_pass3_mx(const ushort_t* __restrict__ xn,
    const float* __restrict__ qarr, const float* __restrict__ warr,
    const float* __restrict__ In, const float* __restrict__ omega,
    ushort_t* __restrict__ mx){
  int idx = blockIdx.x*256+threadIdx.x;
  int d = idx & (D_-1); int c = (idx>>10)&15; int b = idx>>14;
  const ushort_t* xp = xn + ((size_t)b*L_ + c*CL_)*D_ + d;
  ushort_t* op = mx + ((size_t)b*L_ + c*CL_)*D_ + d;
  size_t base = (((size_t)b*NC_+c)*N_)*D_ + d;
  float om = omega[d];
  float q[N_], w[N_], s[N_];
  #pragma unroll
  for(int n=0;n<N_;n++){ q[n]=qarr[d*N_+n]; w[n]=warr[d*N_+n]; s[n]=In[base+(size_t)n*D_]; }
  for(int i=0;i<CL_;i+=8){
    float xv[8];
    #pragma unroll
    for(int j=0;j<8;j++) xv[j]=b2f(xp[(size_t)(i+j)*D_]);
    #pragma unroll
    for(int j=0;j<8;j++){
      float a=0.0f;
      #pragma unroll
      for(int n=0;n<N_;n++){ s[n]=fmaf(q[n],s[n],xv[j]); a=fmaf(w[n],s[n],a); }
      op[(size_t)(i+j)*D_]=f2b(siluf_(a + xv[j]*om));
    }
  }
}

// ---------------- softmax over rows of qk (L cols), write bf16 attn -----------
__global__ __launch_bounds__(256) void softmax_kernel(const float* __restrict__ qk,
    ushort_t* __restrict__ attn){
  size_t row = blockIdx.x;
  const float* p = qk + row*(size_t)L_;
  int t = threadIdx.x;
  float vals[8];
  #pragma unroll
  for(int i=0;i<8;i++) vals[i]=p[i*256+t];
  float m=-__builtin_inff();
  #pragma unroll
  for(int i=0;i<8;i++) m=fmaxf(m,vals[i]);
  m = blockMax(m);
  float s=0.0f;
  #pragma unroll
  for(int i=0;i<8;i++){ vals[i]=__expf(vals[i]-m); s+=vals[i]; }
  s = blockSum(s);
  float inv = 1.0f/s;
  ushort_t* q = attn + row*(size_t)L_;
  #pragma unroll
  for(int i=0;i<8;i++) q[i*256+t]=f2b(vals[i]*inv);
}

// ======================= sync primitives ======================================
// RAW s_barrier, no sched_barrier/memory-asm (m141: order-pinning defeats the
// scheduler). Correctness is pinned ONLY by the VMW points (memory clobber).
#define BAR() __builtin_amdgcn_s_barrier()
#define VMW(n) asm volatile("s_waitcnt vmcnt(" #n ")" ::: "memory")

// ---------------- OLD engine: NT bf16 GEMM 128x128, BK=64 (kept for QKh/QK) ---
#define BAR_ACQ(vm) do{ \
    asm volatile("s_waitcnt vmcnt(" #vm ")" ::: "memory"); \
    __builtin_amdgcn_s_barrier(); }while(0)
#define BAR_REL() do{ \
    asm volatile("" ::: "memory"); \
    __builtin_amdgcn_s_barrier(); \
    asm volatile("" ::: "memory"); }while(0)

template<class Epi>
__global__ __launch_bounds__(256) void gemm_nt(const ushort_t* __restrict__ A,
    const ushort_t* __restrict__ B, int M, int N, int K, Epi epi){
  __shared__ __align__(16) ushort_t As[2][128*64];
  __shared__ __align__(16) ushort_t Bs[2][128*64];
  const int t = threadIdx.x;
  const int wave=t>>6, lane=t&63, quad=lane>>4, l16=lane&15;
  const int bm=blockIdx.x*128, bn=blockIdx.y*128;
  const int wm=(wave>>1)*64, wn=(wave&1)*64;
  const int srow = wave*32 + (lane>>3);
  const int schk = ((lane&7) ^ (lane>>3)) * 8;
  const ushort_t* gA[4]; const ushort_t* gB[4];
  ushort_t *lA[4], *lB[4];
  #pragma unroll
  for(int i=0;i<4;i++){
    gA[i] = A + (size_t)(bm+srow+i*8)*K + schk;
    gB[i] = B + (size_t)(bn+srow+i*8)*K + schk;
    lA[i] = &As[0][(wave*32+i*8)*64];
    lB[i] = &Bs[0][(wave*32+i*8)*64];
  }
  const ushort_t* ra[2][4]; const ushort_t* rb[2][4];
  #pragma unroll
  for(int h=0;h<2;h++)
    #pragma unroll
    for(int i=0;i<4;i++){
      int rrA = wm+i*16+l16, rrB = wn+i*16+l16;
      ra[h][i] = &As[0][rrA*64 + (((h*4+quad)^(rrA&7))*8)];
      rb[h][i] = &Bs[0][rrB*64 + (((h*4+quad)^(rrB&7))*8)];
    }
  floatx4 acc[4][4];
  #pragma unroll
  for(int i=0;i<4;i++)
    #pragma unroll
    for(int j=0;j<4;j++) acc[i][j]=(floatx4){0.f,0.f,0.f,0.f};

  const int nk = K>>6;
  #pragma unroll
  for(int i=0;i<4;i++){ GLL16(gA[i], lA[i]); GLL16(gB[i], lB[i]); }

  for(int t0=0;t0<nk;t0+=2){
    {
      const int k0=(t0+1)<<6;
      #pragma unroll
      for(int i=0;i<4;i++){ GLL16(gA[i]+k0, lA[i]+(128*64)); GLL16(gB[i]+k0, lB[i]+(128*64)); }
    }
    BAR_ACQ(8);
    #pragma unroll
    for(int h=0;h<2;h++){
      short8 af[4], bf[4];
      #pragma unroll
      for(int mt=0;mt<4;mt++) af[mt]=*reinterpret_cast<const short8*>(ra[h][mt]);
      #pragma unroll
      for(int nt=0;nt<4;nt++) bf[nt]=*reinterpret_cast<const short8*>(rb[h][nt]);
      #pragma unroll
      for(int mt=0;mt<4;mt++)
        #pragma unroll
        for(int nt=0;nt<4;nt++)
          acc[mt][nt]=__builtin_amdgcn_mfma_f32_16x16x32_bf16(af[mt],bf[nt],acc[mt][nt],0,0,0);
    }
    BAR_REL();
    if(t0+2<nk){
      const int k0=(t0+2)<<6;
      #pragma unroll
      for(int i=0;i<4;i++){ GLL16(gA[i]+k0, lA[i]); GLL16(gB[i]+k0, lB[i]); }
      BAR_ACQ(8);
    } else {
      BAR_ACQ(0);
    }
    #pragma unroll
    for(int h=0;h<2;h++){
      short8 af[4], bf[4];
      #pragma unroll
      for(int mt=0;mt<4;mt++) af[mt]=*reinterpret_cast<const short8*>(ra[h][mt]+(128*64));
      #pragma unroll
      for(int nt=0;nt<4;nt++) bf[nt]=*reinterpret_cast<const short8*>(rb[h][nt]+(128*64));
      #pragma unroll
      for(int mt=0;mt<4;mt++)
        #pragma unroll
        for(int nt=0;nt<4;nt++)
          acc[mt][nt]=__builtin_amdgcn_mfma_f32_16x16x32_bf16(af[mt],bf[nt],acc[mt][nt],0,0,0);
    }
    BAR_REL();
  }

  #pragma unroll
  for(int mt=0;mt<4;mt++)
    #pragma unroll
    for(int nt=0;nt<4;nt++)
      #pragma unroll
      for(int r=0;r<4;r++){
        int row=bm+wm+mt*16+quad*4+r;
        int col=bn+wn+nt*16+l16;
        epi(acc[mt][nt][r], row, col, 0);
      }
}

// ====== NEW engine v5: 256x256, 8 waves, kh-split, counted vmcnt, raw bars ====
// C[z][m,n]=sum_k A[z][m,k]*B[z][n,k]. BK=64 as two kh halves of 32 elems.
// LDS [buf][kh][256 rows][32 elems] per matrix = 128 KiB total.
// Per tile t (buf = t&1), 4 phases; tile t+1 staged in 4 groups of 2 gll:
//  P1 {rd A kh0 mt0-3 + B kh0; gll A-kh0(t+1); BAR; prio1 16MFMA prio0; BAR}
//  P2 {rd A kh0 mt4-7;         gll B-kh0(t+1); BAR; 16MFMA; VMW(4); BAR}
//  P3 {rd A kh1 mt0-3 + B kh1; gll A-kh1(t+1); BAR; 16MFMA; BAR}
//  P4 {rd A kh1 mt4-7;         gll B-kh1(t+1); BAR; 16MFMA; VMW(4); BAR}
// Ledger (per-wave FIFO, 2 loads/group): at P2-end exactly groups {A-kh0,B-kh0}
// of t+1 (4 loads) are outstanding -> VMW(4) proves t's kh1 (staged at t-1
// P3/P4) landed, read at P3. At P4-end exactly {A-kh1,B-kh1} of t+1 are
// outstanding -> VMW(4) proves t+1's kh0 landed, read at t+1 P1. NEVER drains.
// Cover >= 2 phases per group >> HBM latency. Write-after-read: all stages of
// tile t+1 into buf^1 are issued after tile t-1's end barrier, which ended all
// reads of buf^1. Swizzle: slot s (16B) of row r holds granule s^((r>>1)&3) ->
// ds_read_b128 frag reads are 2 lanes/bank-span (free, m136); gll dest linear,
// source granule pre-swizzled. Requires M%256==0, N%256==0, K%128==0.

#define RA4(buf,kh,mh) \
  af[0]=pA8[(buf)*2048+(kh)*1024+((mh)*4+0)*64+rowA]; \
  af[1]=pA8[(buf)*2048+(kh)*1024+((mh)*4+1)*64+rowA]; \
  af[2]=pA8[(buf)*2048+(kh)*1024+((mh)*4+2)*64+rowA]; \
  af[3]=pA8[(buf)*2048+(kh)*1024+((mh)*4+3)*64+rowA];
#define RB4(buf,kh) \
  bf[0]=pB8[(buf)*2048+(kh)*1024+0*64+rowB]; \
  bf[1]=pB8[(buf)*2048+(kh)*1024+1*64+rowB]; \
  bf[2]=pB8[(buf)*2048+(kh)*1024+2*64+rowB]; \
  bf[3]=pB8[(buf)*2048+(kh)*1024+3*64+rowB];
#define MMA16(mh) \
  __builtin_amdgcn_s_setprio(1); \
  acc[(mh)*4+0][0]=__builtin_amdgcn_mfma_f32_16x16x32_bf16(af[0],bf[0],acc[(mh)*4+0][0],0,0,0); \
  acc[(mh)*4+0][1]=__builtin_amdgcn_mfma_f32_16x16x32_bf16(af[0],bf[1],acc[(mh)*4+0][1],0,0,0); \
  acc[(mh)*4+0][2]=__builtin_amdgcn_mfma_f32_16x16x32_bf16(af[0],bf[2],acc[(mh)*4+0][2],0,0,0); \
  acc[(mh)*4+0][3]=__builtin_amdgcn_mfma_f32_16x16x32_bf16(af[0],bf[3],acc[(mh)*4+0][3],0,0,0); \
  acc[(mh)*4+1][0]=__builtin_amdgcn_mfma_f32_16x16x32_bf16(af[1],bf[0],acc[(mh)*4+1][0],0,0,0); \
  acc[(mh)*4+1][1]=__builtin_amdgcn_mfma_f32_16x16x32_bf16(af[1],bf[1],acc[(mh)*4+1][1],0,0,0); \
  acc[(mh)*4+1][2]=__builtin_amdgcn_mfma_f32_16x16x32_bf16(af[1],bf[2],acc[(mh)*4+1][2],0,0,0); \
  acc[(mh)*4+1][3]=__builtin_amdgcn_mfma_f32_16x16x32_bf16(af[1],bf[3],acc[(mh)*4+1][3],0,0,0); \
  acc[(mh)*4+2][0]=__builtin_amdgcn_mfma_f32_16x16x32_bf16(af[2],bf[0],acc[(mh)*4+2][0],0,0,0); \
  acc[(mh)*4+2][1]=__builtin_amdgcn_mfma_f32_16x16x32_bf16(af[2],bf[1],acc[(mh)*4+2][1],0,0,0); \
  acc[(mh)*4+2][2]=__builtin_amdgcn_mfma_f32_16x16x32_bf16(af[2],bf[2],acc[(mh)*4+2][2],0,0,0); \
  acc[(mh)*4+2][3]=__builtin_amdgcn_mfma_f32_16x16x32_bf16(af[2],bf[3],acc[(mh)*4+2][3],0,0,0); \
  acc[(mh)*4+3][0]=__builtin_amdgcn_mfma_f32_16x16x32_bf16(af[3],bf[0],acc[(mh)*4+3][0],0,0,0); \
  acc[(mh)*4+3][1]=__builtin_amdgcn_mfma_f32_16x16x32_bf16(af[3],bf[1],acc[(mh)*4+3][1],0,0,0); \
  acc[(mh)*4+3][2]=__builtin_amdgcn_mfma_f32_16x16x32_bf16(af[3],bf[2],acc[(mh)*4+3][2],0,0,0); \
  acc[(mh)*4+3][3]=__builtin_amdgcn_mfma_f32_16x16x32_bf16(af[3],bf[3],acc[(mh)*4+3][3],0,0,0); \
  __builtin_amdgcn_s_setprio(0);
// stage group: matrix X in {A,B}, kh, dest buf b, k-elem offset k0 (2 gll)
#define SA2(b,kh,k0) \
  GLL16(gA0+(k0)+(kh)*32, lAd+((b)*2+(kh))*8192); \
  GLL16(gA1+(k0)+(kh)*32, lAd+((b)*2+(kh))*8192+512);
#define SB2(b,kh,k0) \
  GLL16(gB0+(k0)+(kh)*32, lBd+((b)*2+(kh))*8192); \
  GLL16(gB1+(k0)+(kh)*32, lBd+((b)*2+(kh))*8192+512);

#define TILE_S(buf,k1) { \
  short8 af[4], bf[4]; \
  RA4(buf,0,0) RB4(buf,0) \
  SA2((buf)^1,0,k1) \
  BAR(); MMA16(0) BAR(); \
  RA4(buf,0,1) \
  SB2((buf)^1,0,k1) \
  BAR(); MMA16(1) VMW(4); BAR(); \
  RA4(buf,1,0) RB4(buf,1) \
  SA2((buf)^1,1,k1) \
  BAR(); MMA16(0) BAR(); \
  RA4(buf,1,1) \
  SB2((buf)^1,1,k1) \
  BAR(); MMA16(1) VMW(4); BAR(); \
}
#define TILE_E(buf) { \
  short8 af[4], bf[4]; \
  RA4(buf,0,0) RB4(buf,0) \
  BAR(); MMA16(0) BAR(); \
  RA4(buf,0,1) \
  BAR(); MMA16(1) VMW(0); BAR(); \
  RA4(buf,1,0) RB4(buf,1) \
  BAR(); MMA16(0) BAR(); \
  RA4(buf,1,1) \
  BAR(); MMA16(1) \
}

template<class Epi>
__global__ __launch_bounds__(512) void gemm_nt2(const ushort_t* __restrict__ A0,
    const ushort_t* __restrict__ B0, int M, int N, int K,
    size_t za, size_t zb, Epi epi){
  __shared__ __align__(16) ushort_t As[2*2*8192];   // [buf][kh][256][32]
  __shared__ __align__(16) ushort_t Bs[2*2*8192];
  const int t = threadIdx.x;
  const int wave=t>>6, lane=t&63, quad=lane>>4, l16=lane&15;
  // ---- rasterization: supertile (GW x 8) = 32 blocks, XCD-chunked ----
  int bx, by;
  {
    int gx=gridDim.x, gy=gridDim.y;
    int f = blockIdx.y*gx + blockIdx.x;
    if((gy==4 || gy==8) && (gx%(32/gy))==0){
      int GW = 32/gy, nst = gx/GW;
      int s, r;
      if((nst&7)==0){ int xc=f&7; int j=f>>3; s = xc*(nst>>3) + (j>>5); r = j&31; }
      else { s = f>>5; r = f&31; }
      bx = s*GW + (r%GW); by = r/GW;
    } else { bx = blockIdx.x; by = blockIdx.y; }
  }
  const int z = blockIdx.z;
  const ushort_t* A = A0 + (size_t)z*za;
  const ushort_t* B = B0 + (size_t)z*zb;
  const int bm=bx*256, bn=by*256;
  const int wm=(wave>>2)*128, wn=(wave&3)*64;
  // staging pointers: gll covers 16 rows (4 lanes/row); lane l -> row +(l>>2),
  // slot l&3; source granule (l&3)^((l>>3)&3) (pre-swizzled global side).
  const int g8 = ((lane&3) ^ ((lane>>3)&3))*8;
  const ushort_t* gA0 = A + (size_t)(bm + wave*32 + (lane>>2))*K + g8;
  const ushort_t* gA1 = gA0 + (size_t)16*K;
  const ushort_t* gB0 = B + (size_t)(bn + wave*32 + (lane>>2))*K + g8;
  const ushort_t* gB1 = gB0 + (size_t)16*K;
  ushort_t* lAd = As + wave*1024;   // wave*32 rows * 32 elems
  ushort_t* lBd = Bs + wave*1024;
  // frag read bases (short8 units): block*1024 + row*4 + slot,
  // slot = quad ^ ((row>>1)&3); row bits beyond l16 are multiples of 8.
  const short8* pA8 = reinterpret_cast<const short8*>(As);
  const short8* pB8 = reinterpret_cast<const short8*>(Bs);
  const int swl = (l16>>1)&3;
  const int rowA = (wm+l16)*4 + (quad^swl);
  const int rowB = (wn+l16)*4 + (quad^swl);
  floatx4 acc[8][4];
  #pragma unroll
  for(int i=0;i<8;i++)
    #pragma unroll
    for(int j=0;j<4;j++) acc[i][j]=(floatx4){0.f,0.f,0.f,0.f};

  const int nkt = K>>6;   // even, >=2 for all routed shapes
  // prologue: stage tile 0 into buf0 (groups A-kh0, B-kh0, A-kh1, B-kh1)
  SA2(0,0,0) SB2(0,0,0) SA2(0,1,0) SB2(0,1,0)
  VMW(4); BAR();          // kh0 of tile0 landed; kh1 (4 loads) in flight

  for(int t0=0; t0+2<nkt; t0+=2){
    TILE_S(0,(t0+1)<<6)
    TILE_S(1,(t0+2)<<6)
  }
  TILE_S(0,(nkt-1)<<6)    // tile nkt-2 stages the last tile
  TILE_E(1)               // last tile: no staging

  #pragma unroll
  for(int mt=0;mt<8;mt++)
    #pragma unroll
    for(int nt=0;nt<4;nt++)
      #pragma unroll
      for(int r=0;r<4;r++){
        int row=bm+wm+mt*16+quad*4+r;
        int col=bn+wn+nt*16+l16;
        epi(acc[mt][nt][r], row, col, z);
      }
}

// ---------------- epilogues (branch-free; pointers pre-offset) ----------------
struct EpiV {            // v = silu(.+vb); store transposed vT[b][col][l]
  ushort_t* vT; const float* vb;
  __device__ void operator()(float v,int row,int col,int) const {
    float s = siluf_(v + vb[col]);
    int b = row>>11, l = row&(L_-1);
    vT[((size_t)b*V_ + col)*L_ + l] = f2b(s);
  }
};
struct EpiU {            // u = sigmoid(.+b) -> bf16
  ushort_t* u; const float* mxb;
  __device__ void operator()(float v,int row,int col,int) const {
    u[(size_t)row*D_+col]=f2b(sigmoidf_(v+mxb[col]));
  }
};
struct EpiQKh {          // z=silu(.+b); qh=z*ag0+ab0, kh=z*ag1+ab1 (col in [0,Z))
  ushort_t* qh; ushort_t* kh; const float* mxb; const float* ag; const float* ab;
  __device__ void operator()(float v,int row,int col,int) const {
    float z=siluf_(v+mxb[col]);
    qh[(size_t)row*Z_+col]=f2b(z*ag[col]+ab[col]);
    kh[(size_t)row*Z_+col]=f2b(z*ag[Z_+col]+ab[Z_+col]);
  }
};
struct EpiR {            // r = silu(.+b) -> bf16
  ushort_t* r; const float* mxb;
  __device__ void operator()(float v,int row,int col,int) const {
    r[(size_t)row*V_+col]=f2b(siluf_(v+mxb[col]));
  }
};
struct EpiHx {           // hx = .+b -> bf16
  ushort_t* hx; const float* mxb;
  __device__ void operator()(float v,int row,int col,int) const {
    hx[(size_t)row*D_+col]=f2b(v+mxb[col]);
  }
};
struct EpiQK {           // qk = scale*dot + rel_bias[L-1+col-row]
  float* qk; const float* rb;
  __device__ void operator()(float v,int row,int col,int) const {
    qk[(size_t)row*L_+col] = v*0.08838834764831845f + rb[L_-1+col-row];
  }
};
struct EpiH {            // hr = (attn@v) * r, in place over r; z = batch in chunk
  ushort_t* hr; const ushort_t* r;
  __device__ void operator()(float v,int row,int col,int z) const {
    size_t idx = ((size_t)z*L_ + row)*V_ + col;
    hr[idx] = f2b(v * b2f(r[idx]));
  }
};
struct EpiOut {          // h2=silu(hx+g+hb); out = x + u*(h2-x)  (out in d_out)
  float* out; const float* x; const ushort_t* u; const ushort_t* hx; const float* hb;
  __device__ void operator()(float v,int row,int col,int) const {
    size_t idx=(size_t)row*D_+col;
    float h2 = siluf_(b2f(hx[idx]) + v + hb[col]);
    float xv = x[idx];
    out[idx] = xv + b2f(u[idx])*(h2-xv);
  }
};
struct EpiF1 {           // f1 = silu(. + ff_b1) -> bf16
  ushort_t* f1; const float* b1;
  __device__ void operator()(float v,int row,int col,int) const {
    f1[(size_t)row*(2*D_)+col]=f2b(siluf_(v+b1[col]));
  }
};
struct EpiFinal {        // d_out += . + ff_b2 (in place)
  float* dout; const float* b2;
  __device__ void operator()(float v,int row,int col,int) const {
    size_t idx=(size_t)row*D_+col;
    dout[idx] = dout[idx] + v + b2[col];
  }
};

// ---------------- host launch -------------------------------------------------
extern "C" void kernel_launch(void* const* d_in, const int* in_sizes, int n_in,
                              void* d_out, int out_size, void* d_ws, size_t ws_size,
                              hipStream_t stream){
  const float* x        = (const float*)d_in[0];
  const float* norm1_w  = (const float*)d_in[1];
  const float* norm1_b  = (const float*)d_in[2];
  const float* ema_delta= (const float*)d_in[3];
  const float* ema_alpha= (const float*)d_in[4];
  const float* ema_beta = (const float*)d_in[5];
  const float* ema_gamma= (const float*)d_in[6];
  const float* ema_omega= (const float*)d_in[7];
  const float* vproj_w  = (const float*)d_in[8];
  const float* vproj_b  = (const float*)d_in[9];
  const float* mx_w     = (const float*)d_in[10];
  const float* mx_b     = (const float*)d_in[11];
  const float* h_w      = (const float*)d_in[12];
  const float* h_b      = (const float*)d_in[13];
  const float* att_gamma= (const float*)d_in[14];
  const float* att_beta = (const float*)d_in[15];
  const float* rel_bias = (const float*)d_in[16];
  const float* norm2_w  = (const float*)d_in[17];
  const float* norm2_b  = (const float*)d_in[18];
  const float* ff_w1    = (const float*)d_in[19];
  const float* ff_b1    = (const float*)d_in[20];
  const float* ff_w2    = (const float*)d_in[21];
  const float* ff_b2    = (const float*)d_in[22];
  float* dout = (float*)d_out;
  char* ws = (char*)d_ws;

  // ---- adaptive workspace layout ----
  size_t cur = 0;
  auto take = [&](size_t b)->size_t{ size_t o=cur; cur += (b+255)&~255ull; return o; };
  const size_t o_wvT  = take((size_t)V_*D_*2);
  const size_t o_wmxT = take((size_t)4224*D_*2);
  const size_t o_whT  = take((size_t)D_*V_*2);
  const size_t o_wf1T = take((size_t)2*D_*D_*2);
  const size_t o_wf2T = take((size_t)D_*2*D_*2);
  const size_t o_qarr = take((size_t)D_*N_*4);
  const size_t o_warr = take((size_t)D_*N_*4);
  const size_t o_qC   = take((size_t)D_*N_*4);
  const size_t globals_end = cur;

  int g = 0;
  size_t o_xn=0,o_mx=0,o_u=0,o_hx=0,o_r=0,o_qh=0,o_kh=0,o_qk=0,o_at=0;
  for(int cand=8; cand>=1; cand>>=1){
    cur = globals_end;
    size_t xn_o = take((size_t)cand*L_*D_*2);
    size_t mx_o = take((size_t)cand*L_*D_*2);
    size_t u_o  = take((size_t)cand*L_*D_*2);
    size_t hx_o = take((size_t)cand*L_*D_*2);
    size_t r_o  = take((size_t)cand*L_*V_*2);
    size_t qh_o = take((size_t)cand*L_*Z_*2);
    size_t kh_o = take((size_t)cand*L_*Z_*2);
    size_t qk_o, at_o;
    if(cand>=4){ qk_o = xn_o; at_o = xn_o + (size_t)L_*L_*4; }   // overlay dead xn/mx
    else { qk_o = take((size_t)L_*L_*4); at_o = take((size_t)L_*L_*2); }
    if(cur <= ws_size){
      g=cand; o_xn=xn_o; o_mx=mx_o; o_u=u_o; o_hx=hx_o; o_r=r_o;
      o_qh=qh_o; o_kh=kh_o; o_qk=qk_o; o_at=at_o; break;
    }
  }
  if(!g) return;   // ws too small even for per-batch plan

  ushort_t* wvT  = (ushort_t*)(ws+o_wvT);
  ushort_t* wmxT = (ushort_t*)(ws+o_wmxT);
  ushort_t* whT  = (ushort_t*)(ws+o_whT);
  ushort_t* wf1T = (ushort_t*)(ws+o_wf1T);
  ushort_t* wf2T = (ushort_t*)(ws+o_wf2T);
  float* qarr = (float*)(ws+o_qarr);
  float* warr = (float*)(ws+o_warr);
  float* qC   = (float*)(ws+o_qC);
  ushort_t* xn  = (ushort_t*)(ws+o_xn);
  ushort_t* mx  = (ushort_t*)(ws+o_mx);
  ushort_t* u16 = (ushort_t*)(ws+o_u);
  ushort_t* hx16= (ushort_t*)(ws+o_hx);
  ushort_t* r16 = (ushort_t*)(ws+o_r);
  ushort_t* qh  = (ushort_t*)(ws+o_qh);
  ushort_t* kh  = (ushort_t*)(ws+o_kh);
  float*    qk  = (float*)   (ws+o_qk);
  ushort_t* attn= (ushort_t*)(ws+o_at);
  float*    E   = (float*)(ws+o_u);    // overlay: E/In used only before u/hx written
  float*    In  = (float*)(ws+o_hx);
  ushort_t* ybf = xn;                  // overlay: xn/qk dead by LN2
  ushort_t* f1  = r16;                 // overlay: r dead after out GEMM

  // attention batching: attn for nbat batches lives in dead mx region (g>=4)
  int nbat; ushort_t* attnB;
  if(g>=4){ nbat = g/2; attnB = mx; }          // g=8 -> 4 batches (32MB <= mx 32MB)
  else    { nbat = 1;   attnB = attn; }

  // ---- one-time prep ----
  transpose_w<<<dim3(V_/32, D_/32), 256, 0, stream>>>(vproj_w, wvT, D_, V_);
  transpose_w<<<dim3(4224/32, D_/32), 256, 0, stream>>>(mx_w, wmxT, D_, 4224);
  transpose_w<<<dim3(D_/32, V_/32), 256, 0, stream>>>(h_w, whT, V_, D_);
  transpose_w<<<dim3((2*D_)/32, D_/32), 256, 0, stream>>>(ff_w1, wf1T, D_, 2*D_);
  transpose_w<<<dim3(D_/32, (2*D_)/32), 256, 0, stream>>>(ff_w2, wf2T, 2*D_, D_);
  ema_setup<<<(D_*N_)/256, 256, 0, stream>>>(ema_delta, ema_alpha, ema_beta, ema_gamma, qarr, warr, qC);

  // ---- per-group pipeline ----
  for(int gi=0; gi<B_/g; ++gi){
    const int RG = g*L_;
    const float* x_g  = x    + (size_t)gi*RG*D_;
    float*       do_g = dout + (size_t)gi*RG*D_;
    ushort_t*    vT   = (ushort_t*)do_g;   // scratch inside d_out slice (dead before out-write)

    ln_kernel<<<RG, 256, 0, stream>>>(x_g, norm1_w, norm1_b, xn);
    ema_pass1<<<(g*NC_*D_)/256, 256, 0, stream>>>(xn, qarr, E);
    ema_pass2<<<(g*D_)/256, 256, 0, stream>>>(E, qC, In);
    ema_pass3_mx<<<(g*NC_*D_)/256, 256, 0, stream>>>(xn, qarr, warr, In, ema_omega, mx);

    { EpiV e{vT, vproj_b};
      gemm_nt2<<<dim3(RG/256, V_/256), 512, 0, stream>>>(xn, wvT, RG, V_, D_, 0, 0, e); }

    // base GEMM split into 4 column sections (branch-free epilogues)
    { EpiU e{u16, mx_b};
      gemm_nt2<<<dim3(RG/256, D_/256), 512, 0, stream>>>(mx, wmxT, RG, D_, D_, 0, 0, e); }
    { EpiQKh e{qh, kh, mx_b+D_, att_gamma, att_beta};
      gemm_nt<<<dim3(RG/128, Z_/128), 256, 0, stream>>>(mx, wmxT+(size_t)D_*D_, RG, Z_, D_, e); }
    { EpiR e{r16, mx_b+D_+Z_};
      gemm_nt2<<<dim3(RG/256, V_/256), 512, 0, stream>>>(mx, wmxT+(size_t)(D_+Z_)*D_, RG, V_, D_, 0, 0, e); }
    { EpiHx e{hx16, mx_b+D_+Z_+V_};
      gemm_nt2<<<dim3(RG/256, D_/256), 512, 0, stream>>>(mx, wmxT+(size_t)(D_+Z_+V_)*D_, RG, D_, D_, 0, 0, e); }

    // attention: per-batch QK+softmax into chunk buffer, then batched PV GEMM
    for(int q0=0; q0<g; q0+=nbat){
      for(int bi=q0; bi<q0+nbat; ++bi){
        { EpiQK e{qk, rel_bias};
          gemm_nt<<<dim3(L_/128, L_/128), 256, 0, stream>>>(
            qh+(size_t)bi*L_*Z_, kh+(size_t)bi*L_*Z_, L_, L_, Z_, e); }
        softmax_kernel<<<L_, 256, 0, stream>>>(qk, attnB+(size_t)(bi-q0)*L_*L_);
      }
      { EpiH e{r16+(size_t)q0*L_*V_, r16+(size_t)q0*L_*V_};
        gemm_nt2<<<dim3(L_/256, V_/256, nbat), 512, 0, stream>>>(
          attnB, vT+(size_t)q0*V_*L_, L_, V_, L_,
          (size_t)L_*L_, (size_t)V_*L_, e); }
    }

    { EpiOut e{do_g, x_g, u16, hx16, h_b};
      gemm_nt2<<<dim3(RG/256, D_/256), 512, 0, stream>>>(r16, whT, RG, D_, V_, 0, 0, e); }
    ln_kernel<<<RG, 256, 0, stream>>>(do_g, norm2_w, norm2_b, ybf);
    { EpiF1 e{f1, ff_b1};
      gemm_nt2<<<dim3(RG/256, (2*D_)/256), 512, 0, stream>>>(ybf, wf1T, RG, 2*D_, D_, 0, 0, e); }
    { EpiFinal e{do_g, ff_b2};
      gemm_nt2<<<dim3(RG/256, D_/256), 512, 0, stream>>>(f1, wf2T, RG, D_, 2*D_, 0, 0, e); }
  }
}